// Round 1
// baseline (454.999 us; speedup 1.0000x reference)
//
#include <hip/hip_runtime.h>
#include <math.h>

// Problem constants (from reference setup_inputs)
#define B_DIM 8
#define A_DIM 48
#define GF_DIM 256
#define S_DIM 4096
#define P_DIM 32
#define E_DIM 5
#define OHN 100           // sum(SIZES), SIZES = 5 x 20
#define XDIM 356          // OHN + GF
#define NBINS 65536
#define NROWS (B_DIM * S_DIM)   // 32768

// ---------------- wave-level helpers (wave64) ----------------
__device__ __forceinline__ float wave_sum(float v) {
#pragma unroll
    for (int o = 32; o; o >>= 1) v += __shfl_xor(v, o, 64);
    return v;
}
__device__ __forceinline__ float wave_max(float v) {
#pragma unroll
    for (int o = 32; o; o >>= 1) v = fmaxf(v, __shfl_xor(v, o, 64));
    return v;
}

__device__ __forceinline__ float therm_val(int j, float c0, float c1, float c2,
                                           float c3, float c4) {
    int e = j / 20;
    int pos = j - e * 20;
    float ce = (e == 0) ? c0 : (e == 1) ? c1 : (e == 2) ? c2 : (e == 3) ? c3 : c4;
    return ((float)pos < ce) ? 1.0f : 0.0f;
}

// ---------------- K1: per-subset features -> x0 rows (356 f32) ----------------
// Block = 256 thr = 4 waves; 8 subsets/block (2 per wave). masked_vert in LDS.
__global__ __launch_bounds__(256) void k_features(
    const float* __restrict__ vert_feat,   // (B,48,256)
    const float* __restrict__ vert_mask,   // (B,48)
    const float* __restrict__ elem_oh,     // (B,48,5)
    const int*   __restrict__ subsets,     // (B,4096,48)
    float* __restrict__ xbuf)              // (32768, 356)
{
    __shared__ float4 vertm[A_DIM][GF_DIM / 4];   // vert * mask
    __shared__ float  maskL[A_DIM];
    __shared__ int    eiL[A_DIM];

    const int tid  = threadIdx.x;
    const int lane = tid & 63;
    const int w    = tid >> 6;
    const int b    = blockIdx.x >> 9;            // 512 blocks per batch
    const int s0   = (blockIdx.x & 511) * 8;

    if (tid < A_DIM) {
        maskL[tid] = vert_mask[b * A_DIM + tid];
        int ei = 0;
#pragma unroll
        for (int e = 0; e < E_DIM; ++e)
            if (elem_oh[(b * A_DIM + tid) * E_DIM + e] > 0.5f) ei = e;
        eiL[tid] = ei;
    }
    __syncthreads();

    const float4* vb = (const float4*)(vert_feat + (size_t)b * A_DIM * GF_DIM);
    for (int idx = tid; idx < A_DIM * (GF_DIM / 4); idx += 256) {
        float4 v = vb[idx];
        float mk = maskL[idx >> 6];
        v.x *= mk; v.y *= mk; v.z *= mk; v.w *= mk;
        vertm[idx >> 6][idx & 63] = v;
    }
    __syncthreads();

    const int   myei   = (lane < A_DIM) ? eiL[lane] : -1;
    const float mymask = (lane < A_DIM) ? maskL[lane] : 0.0f;

#pragma unroll
    for (int i = 0; i < 2; ++i) {
        const int s = s0 + w * 2 + i;
        const int* fp = subsets + ((size_t)b * S_DIM + s) * A_DIM;
        int myflag = (lane < A_DIM) ? fp[lane] : 0;
        float fcoef = (float)myflag * mymask;    // subsets_masked coefficient

        // exact integer counts per element via ballot
        float c0, c1, c2, c3, c4;
        {
            unsigned long long m0 = __ballot(myflag != 0 && myei == 0);
            unsigned long long m1 = __ballot(myflag != 0 && myei == 1);
            unsigned long long m2 = __ballot(myflag != 0 && myei == 2);
            unsigned long long m3 = __ballot(myflag != 0 && myei == 3);
            unsigned long long m4 = __ballot(myflag != 0 && myei == 4);
            c0 = (float)__popcll(m0); c1 = (float)__popcll(m1);
            c2 = (float)__popcll(m2); c3 = (float)__popcll(m3);
            c4 = (float)__popcll(m4);
        }
        float ssize = wave_sum(fcoef) + 1e-4f;

        // sws: sum of selected masked_vert rows; lane owns 4 contiguous cols
        float4 acc = make_float4(0.f, 0.f, 0.f, 0.f);
        for (int a = 0; a < A_DIM; ++a) {
            float cf = __shfl(fcoef, a, 64);
            float4 vv = vertm[a][lane];
            acc.x = fmaf(cf, vv.x, acc.x);
            acc.y = fmaf(cf, vv.y, acc.y);
            acc.z = fmaf(cf, vv.z, acc.z);
            acc.w = fmaf(cf, vv.w, acc.w);
        }
        float inv = 1.0f / ssize;
        float4 mv = make_float4(acc.x * inv, acc.y * inv, acc.z * inv, acc.w * inv);

        // instance norm over 256 cols (wave butterfly)
        float t = wave_sum(mv.x + mv.y + mv.z + mv.w);
        float m = t * (1.0f / 256.0f);
        float dx = mv.x - m, dy = mv.y - m, dz = mv.z - m, dw = mv.w - m;
        float q = wave_sum(dx * dx + dy * dy + dz * dz + dw * dw);
        float rs = 1.0f / sqrtf(q * (1.0f / 256.0f) + 1e-5f);

        float* xr = xbuf + ((size_t)b * S_DIM + s) * XDIM;
        // thermometer one-hot (100)
        xr[lane] = therm_val(lane, c0, c1, c2, c3, c4);
        if (lane < OHN - 64)
            xr[lane + 64] = therm_val(lane + 64, c0, c1, c2, c3, c4);
        // normed features (256)
        *(float4*)(xr + OHN + lane * 4) =
            make_float4(dx * rs, dy * rs, dz * rs, dw * rs);
    }
}

// ---------------- GEMM + fused epilogue ----------------
// Block: 32 rows x 256 cols. Thread: 8 rows x 4 cols. Wave w owns rows 8w..8w+7
// entirely (64 lanes x 4 cols = 256 cols) -> row reductions are wave butterflies.
// ACT: 0 = relu, 1 = leaky(0.01). relu(leaky(z)) == relu(z), so l2b uses ACT=0.
template <int KDIM, int ACT, bool DO_NORM, bool DO_SCORE>
__global__ __launch_bounds__(256) void k_mlp(
    const float* xin, float* xout,                   // row stride XDIM, may alias
    const float* __restrict__ W,                     // (KDIM,256) row-major
    const float* __restrict__ bias,                  // (256)
    const float* __restrict__ sW,                    // (256) or null
    const float* __restrict__ sb,                    // (1) or null
    float* __restrict__ scores)                      // (32768) or null
{
    constexpr int KP = KDIM + 4;
    constexpr int K4 = KDIM / 4;
    __shared__ float xs[32][KP];

    const int tid  = threadIdx.x;
    const int row0 = blockIdx.x * 32;

    for (int idx = tid; idx < 32 * K4; idx += 256) {
        const int r = idx / K4;
        const int c = idx - r * K4;
        *(float4*)&xs[r][c * 4] =
            *(const float4*)(xin + (size_t)(row0 + r) * XDIM + c * 4);
    }
    __syncthreads();

    const int lane = tid & 63;
    const int r0   = (tid >> 6) * 8;
    const int c0   = lane * 4;

    float acc[8][4];
#pragma unroll
    for (int r = 0; r < 8; ++r) {
        acc[r][0] = 0.f; acc[r][1] = 0.f; acc[r][2] = 0.f; acc[r][3] = 0.f;
    }

    for (int k0 = 0; k0 < KDIM; k0 += 4) {
        float4 wv0 = *(const float4*)(W + (size_t)(k0 + 0) * GF_DIM + c0);
        float4 wv1 = *(const float4*)(W + (size_t)(k0 + 1) * GF_DIM + c0);
        float4 wv2 = *(const float4*)(W + (size_t)(k0 + 2) * GF_DIM + c0);
        float4 wv3 = *(const float4*)(W + (size_t)(k0 + 3) * GF_DIM + c0);
#pragma unroll
        for (int r = 0; r < 8; ++r) {
            float4 xv = *(const float4*)&xs[r0 + r][k0];
            acc[r][0] = fmaf(xv.x, wv0.x, acc[r][0]);
            acc[r][1] = fmaf(xv.x, wv0.y, acc[r][1]);
            acc[r][2] = fmaf(xv.x, wv0.z, acc[r][2]);
            acc[r][3] = fmaf(xv.x, wv0.w, acc[r][3]);
            acc[r][0] = fmaf(xv.y, wv1.x, acc[r][0]);
            acc[r][1] = fmaf(xv.y, wv1.y, acc[r][1]);
            acc[r][2] = fmaf(xv.y, wv1.z, acc[r][2]);
            acc[r][3] = fmaf(xv.y, wv1.w, acc[r][3]);
            acc[r][0] = fmaf(xv.z, wv2.x, acc[r][0]);
            acc[r][1] = fmaf(xv.z, wv2.y, acc[r][1]);
            acc[r][2] = fmaf(xv.z, wv2.z, acc[r][2]);
            acc[r][3] = fmaf(xv.z, wv2.w, acc[r][3]);
            acc[r][0] = fmaf(xv.w, wv3.x, acc[r][0]);
            acc[r][1] = fmaf(xv.w, wv3.y, acc[r][1]);
            acc[r][2] = fmaf(xv.w, wv3.z, acc[r][2]);
            acc[r][3] = fmaf(xv.w, wv3.w, acc[r][3]);
        }
    }

    // bias + activation
    float4 bv = *(const float4*)(bias + c0);
#pragma unroll
    for (int r = 0; r < 8; ++r) {
        acc[r][0] += bv.x; acc[r][1] += bv.y; acc[r][2] += bv.z; acc[r][3] += bv.w;
#pragma unroll
        for (int c = 0; c < 4; ++c) {
            float z = acc[r][c];
            if (ACT == 0) z = fmaxf(z, 0.0f);
            else          z = (z > 0.0f) ? z : 0.01f * z;
            acc[r][c] = z;
        }
    }

    if (DO_NORM) {
#pragma unroll
        for (int r = 0; r < 8; ++r) {
            float t = wave_sum(acc[r][0] + acc[r][1] + acc[r][2] + acc[r][3]);
            float m = t * (1.0f / 256.0f);
            float d0 = acc[r][0] - m, d1 = acc[r][1] - m;
            float d2 = acc[r][2] - m, d3 = acc[r][3] - m;
            float q = wave_sum(d0 * d0 + d1 * d1 + d2 * d2 + d3 * d3);
            float rs = 1.0f / sqrtf(q * (1.0f / 256.0f) + 1e-5f);
            acc[r][0] = d0 * rs; acc[r][1] = d1 * rs;
            acc[r][2] = d2 * rs; acc[r][3] = d3 * rs;
        }
    }

    if (DO_SCORE) {
        float4 sv = *(const float4*)(sW + c0);
        float sbv = sb[0];
#pragma unroll
        for (int r = 0; r < 8; ++r) {
            float p = acc[r][0] * sv.x + acc[r][1] * sv.y +
                      acc[r][2] * sv.z + acc[r][3] * sv.w;
            p = wave_sum(p) + sbv;
            if (lane == r) scores[row0 + r0 + r] = p;
        }
    } else {
#pragma unroll
        for (int r = 0; r < 8; ++r)
            *(float4*)(xout + (size_t)(row0 + r0 + r) * XDIM + c0) =
                make_float4(acc[r][0], acc[r][1], acc[r][2], acc[r][3]);
    }
}

// ---------------- softmax over S=4096 per batch (in-place on scores) ----------
__global__ __launch_bounds__(256) void k_softmax(float* __restrict__ probs) {
    const int b   = blockIdx.x;
    const int tid = threadIdx.x;
    __shared__ float redA[4];
    __shared__ float redB[4];
    float* sp = probs + (size_t)b * S_DIM;

    float v[16];
    float mx = -INFINITY;
#pragma unroll
    for (int i = 0; i < 16; ++i) {
        v[i] = sp[tid + i * 256];
        mx = fmaxf(mx, v[i]);
    }
    mx = wave_max(mx);
    if ((tid & 63) == 0) redA[tid >> 6] = mx;
    __syncthreads();
    mx = fmaxf(fmaxf(redA[0], redA[1]), fmaxf(redA[2], redA[3]));

    float sum = 0.f;
#pragma unroll
    for (int i = 0; i < 16; ++i) {
        v[i] = expf(v[i] - mx);
        sum += v[i];
    }
    sum = wave_sum(sum);
    if ((tid & 63) == 0) redB[tid >> 6] = sum;
    __syncthreads();
    float tot = redB[0] + redB[1] + redB[2] + redB[3];
    float inv = 1.0f / tot;
#pragma unroll
    for (int i = 0; i < 16; ++i) sp[tid + i * 256] = v[i] * inv;
}

// ---------------- zero + scatter ----------------
__global__ __launch_bounds__(256) void k_zero(float* __restrict__ p, int n) {
    int i = blockIdx.x * 256 + threadIdx.x;
    if (i < n) p[i] = 0.0f;
}

__global__ __launch_bounds__(256) void k_scatter(
    const int*   __restrict__ mass_idx,    // (B,S,P) flat
    const float* __restrict__ intensity,   // (B,S,P) flat
    const float* __restrict__ probs,       // (B,S)
    float* __restrict__ spect)             // (B,NBINS)
{
    int i  = blockIdx.x * 256 + threadIdx.x;   // < B*S*P = 1048576 exactly
    int bs = i >> 5;                           // b*S + s  (P = 32)
    int b  = i >> 17;                          // S*P = 131072 = 2^17
    float w = intensity[i] * probs[bs];
    unsafeAtomicAdd(spect + ((size_t)b << 16) + mass_idx[i], w);
}

// ---------------- launch ----------------
extern "C" void kernel_launch(void* const* d_in, const int* in_sizes, int n_in,
                              void* d_out, int out_size, void* d_ws, size_t ws_size,
                              hipStream_t stream) {
    const float* vert_feat = (const float*)d_in[0];
    const float* vert_mask = (const float*)d_in[1];
    const float* elem_oh   = (const float*)d_in[2];
    // d_in[3] adj_oh unused; d_in[5] atom_subsets_peaks unused
    const int*   subsets   = (const int*)d_in[4];
    const int*   mass_idx  = (const int*)d_in[6];
    const float* intensity = (const float*)d_in[7];
    const float* combine_W = (const float*)d_in[8];
    const float* combine_b = (const float*)d_in[9];
    const float* l1_W      = (const float*)d_in[10];
    const float* l1_b      = (const float*)d_in[11];
    const float* l2a_W     = (const float*)d_in[12];
    const float* l2a_b     = (const float*)d_in[13];
    const float* l2b_W     = (const float*)d_in[14];
    const float* l2b_b     = (const float*)d_in[15];
    const float* score_W   = (const float*)d_in[16];
    const float* score_b   = (const float*)d_in[17];

    float* out   = (float*)d_out;
    float* spect = out;                          // B*NBINS = 524288
    float* probs = out + (size_t)B_DIM * NBINS;  // B*S     = 32768 (scores->probs in place)
    float* xbuf  = (float*)d_ws;                 // 32768 x 356 f32 (~46.7 MB)

    // K1: features -> x0 (32768 x 356)
    k_features<<<4096, 256, 0, stream>>>(vert_feat, vert_mask, elem_oh, subsets, xbuf);
    // K2: combine (K=356), relu + inorm, in-place
    k_mlp<356, 0, true, false><<<1024, 256, 0, stream>>>(
        xbuf, xbuf, combine_W, combine_b, nullptr, nullptr, nullptr);
    // K3: l1, relu
    k_mlp<256, 0, false, false><<<1024, 256, 0, stream>>>(
        xbuf, xbuf, l1_W, l1_b, nullptr, nullptr, nullptr);
    // K4: l2a, leaky
    k_mlp<256, 1, false, false><<<1024, 256, 0, stream>>>(
        xbuf, xbuf, l2a_W, l2a_b, nullptr, nullptr, nullptr);
    // K5: l2b, leaky->relu == relu, + inorm + score (writes scores into probs region)
    k_mlp<256, 0, true, true><<<1024, 256, 0, stream>>>(
        xbuf, xbuf, l2b_W, l2b_b, score_W, score_b, probs);
    // K6: softmax per batch (in place on probs)
    k_softmax<<<B_DIM, 256, 0, stream>>>(probs);
    // K7: zero spect, then scatter-add
    k_zero<<<(B_DIM * NBINS) / 256, 256, 0, stream>>>(spect, B_DIM * NBINS);
    k_scatter<<<(B_DIM * S_DIM * P_DIM) / 256, 256, 0, stream>>>(
        mass_idx, intensity, probs, spect);
}